// Round 12
// baseline (92.491 us; speedup 1.0000x reference)
//
#include <hip/hip_runtime.h>
#include <hip/hip_bf16.h>

// Problem constants (fixed by the reference).
#define BB 32
#define CC 32
#define PP 4096      // H*W
#define KS 9
#define KK 64        // output channels
#define CK 288       // C*KS
#define PADP 4100    // u64 stride per gh-section (pad vs 4096)

typedef __attribute__((ext_vector_type(8))) short short8;
typedef __attribute__((ext_vector_type(4))) float f32x4;
typedef __attribute__((ext_vector_type(4))) int int4v;
typedef __attribute__((ext_vector_type(2))) unsigned int u32x2;
typedef __attribute__((ext_vector_type(4))) unsigned int u32x4;
typedef __attribute__((ext_vector_type(16))) float f32x16;

__device__ inline unsigned int f2bf(float f) {
    __hip_bfloat16 h = __float2bfloat16(f);
    return (unsigned int)__builtin_bit_cast(unsigned short, h);
}

// ---- prep: W -> wa4 bf16, K=8-quarter A-fragments (4 real j-slots/lane).
// u16 flat: i = ((qq*9 + kc)*2 + mt)*256 + l*4 + j
//   -> A[m = ko = mt*32 + (l&31)][k-slot j of quarter qq, gh=(l>>5)]
//   channel c = qq*8 + (l>>5)*4 + j ; value = w[ko][c*KS + kc].
// 18432 elems = KK*CK exactly (bijective).
__global__ __launch_bounds__(256)
void prep_wa4_kernel(const float* __restrict__ w, unsigned short* __restrict__ wa4) {
    const int i = blockIdx.x * 256 + threadIdx.x;
    if (i >= KK * CK) return;
    const int j    = i & 3;
    const int l    = (i >> 2) & 63;
    const int mt   = (i >> 8) & 1;
    const int rest = i >> 9;            // qq*9 + kc
    const int qq   = rest / 9;
    const int kc   = rest - qq * 9;
    const int ko   = (mt << 5) + (l & 31);
    const int c    = (qq << 3) + (((l >> 5) & 1) << 2) + j;
    wa4[i] = (unsigned short)f2bf(w[ko * CK + c * KS + kc]);
}

// ---- fused main v8: quarter-pipelined LDS-gather kernel.
// R11 ledger: two-dispatch xt plans pay an unavoidable ~13us cold-HBM gather
// tax (R7 measured; R8 TLP-null; R9/R10 cross-dispatch L2 handoff impossible;
// R11 coop sync unavailable). So serve gathers from LDS (v7 plan) with v7's
// three defects fixed: (1) wa precomputed by prep (was: per-block scattered
// w-rebuild); (2) staging double-buffered per 8-channel quarter -- global
// loads for quarter i+1 fly DURING compute of quarter i (compute is pure-LDS,
// so no vmcnt drain mid-compute); (3) x re-read is L2-served (32 blocks/XCD
// share 4 b-slices = 2MB fp32).
// MFMA: verified 32x32x16 maps with j>=4 zero-padded on BOTH A and B
// (zero products) => effective K=8/quarter, no unverified layouts.
// LDS: xq 2 bufs x [2 gh][4100 px] u64 (ch-quad packed) = 131,200 B
//    + wsl 9,216 B wa slot = 140,416 B -> 1 block/CU, 16 waves.
__global__ __launch_bounds__(1024)
void abc_fused8_kernel(const float* __restrict__ x,
                       const unsigned short* __restrict__ wa4,
                       const int* __restrict__ idx,
                       float* __restrict__ out) {
    __shared__ unsigned long long xq[2][2 * PADP];   // 131,200 B
    __shared__ unsigned int wsl[2304];               //   9,216 B
    const int t    = threadIdx.x;
    const int l    = t & 63;
    const int wv   = t >> 6;                          // wave 0..15
    const int blk  = blockIdx.x;
    const int b    = ((blk & 7) << 2) | ((blk >> 3) & 3);
    const int pb   = blk >> 5;                        // 0..7
    const int p0   = pb * 512 + wv * 32;              // wave's 32 pixels
    const int gpix = l & 31;                          // B-frag n = pixel
    const int gh   = l >> 5;                          // B-frag k-group

    // neighbor indices for this lane's pixel
    int q[KS];
    {
        const int* ip = idx + (size_t)(p0 + gpix) * KS;
#pragma unroll
        for (int kc = 0; kc < KS; ++kc) q[kc] = ip[kc];
    }

    const float* xb = x + (size_t)b * CC * PP;
    const unsigned int* wag = (const unsigned int*)wa4;

    f32x16 acc[2];
#pragma unroll
    for (int i = 0; i < 16; ++i) { acc[0][i] = 0.f; acc[1][i] = 0.f; }

    // ---- prologue: issue quarter-0 x loads (8 f32x4 -> px 4t..4t+3, ch 0..7)
    // and quarter-0 wa loads.
    f32x4 xr[8];
#pragma unroll
    for (int ch = 0; ch < 8; ++ch)
        xr[ch] = *(const f32x4*)(xb + (size_t)ch * PP + 4 * t);
    unsigned int wr0 = wag[t];
    unsigned int wr1 = wag[1024 + t];
    unsigned int wr2 = 0;
    if (t < 256) wr2 = wag[2048 + t];

#pragma unroll 1
    for (int qq = 0; qq < 4; ++qq) {
        // ---- write staged regs -> LDS (vmcnt drained here, after a full
        // compute phase of latency-hiding). Pack ch-quads into u64 per px.
#pragma unroll
        for (int g2 = 0; g2 < 2; ++g2) {
            unsigned int lo[4], hi[4];
#pragma unroll
            for (int jp = 0; jp < 4; ++jp) {
                lo[jp] = f2bf(xr[4 * g2 + 0][jp]) | (f2bf(xr[4 * g2 + 1][jp]) << 16);
                hi[jp] = f2bf(xr[4 * g2 + 2][jp]) | (f2bf(xr[4 * g2 + 3][jp]) << 16);
            }
            u32x4* d = (u32x4*)&xq[qq & 1][(size_t)g2 * PADP + 4 * t];
            d[0] = (u32x4){lo[0], hi[0], lo[1], hi[1]};
            d[1] = (u32x4){lo[2], hi[2], lo[3], hi[3]};
        }
        wsl[t] = wr0;
        wsl[1024 + t] = wr1;
        if (t < 256) wsl[2048 + t] = wr2;
        __syncthreads();

        // ---- issue NEXT-quarter loads now; compute below is pure-LDS so
        // these stay in flight until the next pack's vmcnt.
        if (qq < 3) {
#pragma unroll
            for (int ch = 0; ch < 8; ++ch)
                xr[ch] = *(const f32x4*)(xb + (size_t)((qq + 1) * 8 + ch) * PP + 4 * t);
            const int base = (qq + 1) * 2304;
            wr0 = wag[base + t];
            wr1 = wag[base + 1024 + t];
            if (t < 256) wr2 = wag[base + 2048 + t];
        }

        // ---- compute quarter qq: per kc one u64 LDS gather (B) + 2 A-reads.
#pragma unroll
        for (int kc = 0; kc < KS; ++kc) {
            const u32x2 bg = *(const u32x2*)&xq[qq & 1][(size_t)gh * PADP + q[kc]];
            const int4v bi = {(int)bg[0], (int)bg[1], 0, 0};
            const short8 b8 = __builtin_bit_cast(short8, bi);
#pragma unroll
            for (int mt = 0; mt < 2; ++mt) {
                const u32x2 ag = *(const u32x2*)&wsl[((kc * 2 + mt) * 64 + l) * 2];
                const int4v ai = {(int)ag[0], (int)ag[1], 0, 0};
                const short8 a8 = __builtin_bit_cast(short8, ai);
                acc[mt] = __builtin_amdgcn_mfma_f32_32x32x16_bf16(a8, b8, acc[mt], 0, 0, 0);
            }
        }
        __syncthreads();   // readers done; next iter overwrites wsl + other buf
    }

    // ---- epilogue (v5/v7-verified D map): row=(r&3)+8*(r>>2)+4*gh+32*mt,
    // col = gpix; each store covers two full 128B lines per wave. NT stores.
    float* ob = out + (size_t)b * KK * PP + p0 + gpix;
#pragma unroll
    for (int mt = 0; mt < 2; ++mt)
#pragma unroll
        for (int r = 0; r < 16; ++r) {
            const int row = (mt << 5) + (r & 3) + ((r >> 2) << 3) + (gh << 2);
            __builtin_nontemporal_store(acc[mt][r], ob + (size_t)row * PP);
        }
}

// ---- fallback (ws too small): round-2 VALU kernel ----
__global__ __launch_bounds__(256)
void abc_valu_kernel(const float* __restrict__ x, const float* __restrict__ w,
                     const int* __restrict__ idx, float* __restrict__ out) {
    __shared__ float xrow[PP];
    const int t = threadIdx.x;
    const int b = blockIdx.x >> 4;
    const int p = ((blockIdx.x & 15) << 8) + t;
    int q[KS];
#pragma unroll
    for (int k = 0; k < KS; ++k) q[k] = idx[p * KS + k];
    float acc[KK];
#pragma unroll
    for (int i = 0; i < KK; ++i) acc[i] = 0.0f;
    const float* xb = x + (size_t)b * CC * PP;
#pragma unroll 1
    for (int c = 0; c < CC; ++c) {
        const float4* src = (const float4*)(xb + (size_t)c * PP);
        float4* dst = (float4*)xrow;
#pragma unroll
        for (int j = 0; j < 4; ++j) dst[j * 256 + t] = src[j * 256 + t];
        __syncthreads();
        float xv[KS];
#pragma unroll
        for (int k = 0; k < KS; ++k) xv[k] = xrow[q[k]];
#pragma unroll
        for (int k = 0; k < KS; ++k) {
            const int col = c * KS + k;
#pragma unroll
            for (int ko = 0; ko < KK; ++ko)
                acc[ko] += xv[k] * w[ko * CK + col];
        }
        __syncthreads();
    }
    float* ob = out + (size_t)b * KK * PP + p;
#pragma unroll
    for (int ko = 0; ko < KK; ++ko)
        ob[(size_t)ko * PP] = acc[ko];
}

extern "C" void kernel_launch(void* const* d_in, const int* in_sizes, int n_in,
                              void* d_out, int out_size, void* d_ws, size_t ws_size,
                              hipStream_t stream) {
    const float* x  = (const float*)d_in[0];
    const float* w  = (const float*)d_in[1];
    const int* idx  = (const int*)d_in[2];
    float* out      = (float*)d_out;

    const size_t need = (size_t)KK * CK * 2;   // 36,864 B (wa4 only)

    if (ws_size >= need) {
        unsigned short* wa4 = (unsigned short*)d_ws;
        prep_wa4_kernel<<<(KK * CK + 255) / 256, 256, 0, stream>>>(w, wa4);
        abc_fused8_kernel<<<256, 1024, 0, stream>>>(x, wa4, idx, out);
    } else {
        abc_valu_kernel<<<BB * (PP / 256), 256, 0, stream>>>(x, w, idx, out);
    }
}

// Round 13
// 86.353 us; speedup vs baseline: 1.0711x; 1.0711x over previous
//
#include <hip/hip_runtime.h>
#include <hip/hip_bf16.h>

// Problem constants (fixed by the reference).
#define BB 32
#define CC 32
#define PP 4096      // H*W
#define KS 9
#define KK 64        // output channels
#define CK 288       // C*KS

typedef __attribute__((ext_vector_type(8))) short short8;
typedef __attribute__((ext_vector_type(4))) float float4v;
typedef __attribute__((ext_vector_type(4))) int int4v;

__device__ inline unsigned short f2bf(float f) {
    __hip_bfloat16 h = __float2bfloat16(f);
    return __builtin_bit_cast(unsigned short, h);
}

// ---- prep (merged): blocks [0,512) transpose x -> xt bf16 pixel-major;
//      blocks [512,584) swizzle W -> wa bf16 in MFMA A-fragment order.
// (R3 champion build, byte-identical.)
__global__ __launch_bounds__(256)
void prep_kernel(const float* __restrict__ x, const float* __restrict__ w,
                 unsigned short* __restrict__ xt, unsigned short* __restrict__ wa) {
    const int t = threadIdx.x;
    const int blk = blockIdx.x;
    if (blk < 512) {
        const int b = blk >> 4;
        const int p = ((blk & 15) << 8) + t;
        const float* xb = x + (size_t)b * CC * PP + p;
        unsigned int buf[16];
#pragma unroll
        for (int c2 = 0; c2 < 16; ++c2) {
            float lo = xb[(size_t)(2 * c2) * PP];
            float hi = xb[(size_t)(2 * c2 + 1) * PP];
            buf[c2] = (unsigned int)f2bf(lo) | ((unsigned int)f2bf(hi) << 16);
        }
        uint4* dst = (uint4*)(xt + ((size_t)b * PP + p) * CC);
        const uint4* s = (const uint4*)buf;
#pragma unroll
        for (int j = 0; j < 4; ++j) dst[j] = s[j];
    } else {
        int i = (blk - 512) * 256 + t;
        if (i < KK * CK) {
            int j  = i & 7;
            int l  = (i >> 3) & 63;
            int mt = (i >> 9) & 3;
            int kc = i >> 11;                 // = neighbor k
            int c  = ((l >> 4) << 3) + j;
            int ko = (mt << 4) + (l & 15);
            wa[i] = f2bf(w[ko * CK + c * KS + kc]);
        }
    }
}

// ---- main v9 = v4 champion + in-kernel L2 warm-up.
// R7/R12 diagnosis: cold pass fetches 14.6MB at ~20% DRAM efficiency
// (random 64B bursts) = ~13us tax; R8 proved MLP can't hide it (it's a
// bandwidth-efficiency loss, not latency). Fix: each block STREAMS a
// coalesced 8KB chunk of its b-slice at kernel start (32 blocks/b on one
// XCD cover the full 256KB slice) into kept-alive VGPRs -> xt enters
// L2/L3 at full-burst efficiency; the random gathers then cache-hit.
// No wait needed: gathers consume lines whenever they arrive; keep-alive
// asm sits after the MFMA loop where vmcnt is long drained.
__global__ __launch_bounds__(256, 4)
void abc_mfma9_kernel(const unsigned short* __restrict__ xt,
                      const unsigned short* __restrict__ wa,
                      const int* __restrict__ idx,
                      float* __restrict__ out) {
    __shared__ unsigned short was[KK * CK];          // 36864 B
    const int t    = threadIdx.x;
    const int l    = t & 63;
    const int w    = t >> 6;
    const int blk  = blockIdx.x;
    const int b    = ((blk & 7) << 2) | ((blk >> 3) & 3);
    const int tile = blk >> 5;                               // 0..31
    const int p0   = (tile << 7) + (w << 5);                 // wave's 32 pixels
    const int lo16 = l & 15;
    const int quad = l >> 4;

    const unsigned short* xtb = xt + (size_t)b * PP * CC;

    // ---- L2 warm-up: block's 8KB chunk, coalesced, issued FIRST.
    uint4 wu0, wu1;
    {
        const uint4* wsrc = (const uint4*)(xtb + (size_t)tile * 4096);
        wu0 = wsrc[t];
        wu1 = wsrc[t + 256];
    }

    // stage wa -> LDS (2304 uint4, 9 per thread, coalesced)
    {
        const uint4* s = (const uint4*)wa;
        uint4* d = (uint4*)was;
#pragma unroll
        for (int j = 0; j < 9; ++j) d[t + 256 * j] = s[t + 256 * j];
    }

    // gather-lane role: pixel gpix = l>>2 (within nt half), chunk l&3
    const int gpix   = l >> 2;
    const int gchunk = l & 3;
    int q[2][KS];
#pragma unroll
    for (int nt = 0; nt < 2; ++nt) {
        const int pl = p0 + nt * 16 + gpix;
#pragma unroll
        for (int kc = 0; kc < KS; ++kc) q[nt][kc] = idx[pl * KS + kc];
    }

    // bpermute source byte-addr: fragment lane l pulls from lane 4*(l&15)+(l>>4)
    const int src4 = (((lo16 << 2) | quad) << 2);

    float4v acc[8];   // [mt][nt] -> acc[mt*2+nt]
#pragma unroll
    for (int i = 0; i < 8; ++i) acc[i] = (float4v){0.f, 0.f, 0.f, 0.f};

    __syncthreads();

    // 3-deep register pipeline over kc (full unroll -> static indexing)
    int4v g[3][2];
#pragma unroll
    for (int kk = 0; kk < 2; ++kk)
#pragma unroll
        for (int nt = 0; nt < 2; ++nt)
            g[kk][nt] = *(const int4v*)(xtb + (size_t)q[nt][kk] * CC + (gchunk << 3));

#pragma unroll
    for (int kc = 0; kc < KS; ++kc) {
        // issue gathers for kc+2 (no WAR: 3 buffers)
        if (kc + 2 < KS) {
            const int nb = (kc + 2) % 3;
#pragma unroll
            for (int nt = 0; nt < 2; ++nt)
                g[nb][nt] = *(const int4v*)(xtb + (size_t)q[nt][kc + 2] * CC + (gchunk << 3));
        }
        // redistribute current buffer into MFMA B-fragment order
        const int cb = kc % 3;
        short8 bf[2];
#pragma unroll
        for (int nt = 0; nt < 2; ++nt) {
            int4v r;
#pragma unroll
            for (int j = 0; j < 4; ++j)
                r[j] = __builtin_amdgcn_ds_bpermute(src4, g[cb][nt][j]);
            bf[nt] = __builtin_bit_cast(short8, r);
        }
#pragma unroll
        for (int mt = 0; mt < 4; ++mt) {
            const short8 a = *(const short8*)(was + ((size_t)(kc * 4 + mt) * 64 + l) * 8);
#pragma unroll
            for (int nt = 0; nt < 2; ++nt)
                acc[mt * 2 + nt] =
                    __builtin_amdgcn_mfma_f32_16x16x32_bf16(a, bf[nt], acc[mt * 2 + nt], 0, 0, 0);
        }
    }

    // keep warm-up registers alive (loads long since landed; no wait here)
    asm volatile("" :: "v"(wu0.x), "v"(wu0.y), "v"(wu0.z), "v"(wu0.w),
                       "v"(wu1.x), "v"(wu1.y), "v"(wu1.z), "v"(wu1.w));

    // D layout: m(ko_sub)=quad*4+r, n(pixel)=lo16. Nontemporal stores.
    float* ob = out + (size_t)b * KK * PP + p0 + lo16;
#pragma unroll
    for (int mt = 0; mt < 4; ++mt) {
        float* om = ob + (size_t)(mt * 16 + quad * 4) * PP;
#pragma unroll
        for (int r = 0; r < 4; ++r)
#pragma unroll
            for (int nt = 0; nt < 2; ++nt)
                __builtin_nontemporal_store(acc[mt * 2 + nt][r],
                                            om + (size_t)r * PP + nt * 16);
    }
}

// ---- fallback (ws too small): round-2 VALU kernel ----
__global__ __launch_bounds__(256)
void abc_valu_kernel(const float* __restrict__ x, const float* __restrict__ w,
                     const int* __restrict__ idx, float* __restrict__ out) {
    __shared__ float xrow[PP];
    const int t = threadIdx.x;
    const int b = blockIdx.x >> 4;
    const int p = ((blockIdx.x & 15) << 8) + t;
    int q[KS];
#pragma unroll
    for (int k = 0; k < KS; ++k) q[k] = idx[p * KS + k];
    float acc[KK];
#pragma unroll
    for (int i = 0; i < KK; ++i) acc[i] = 0.0f;
    const float* xb = x + (size_t)b * CC * PP;
#pragma unroll 1
    for (int c = 0; c < CC; ++c) {
        const float4* src = (const float4*)(xb + (size_t)c * PP);
        float4* dst = (float4*)xrow;
#pragma unroll
        for (int j = 0; j < 4; ++j) dst[j * 256 + t] = src[j * 256 + t];
        __syncthreads();
        float xv[KS];
#pragma unroll
        for (int k = 0; k < KS; ++k) xv[k] = xrow[q[k]];
#pragma unroll
        for (int k = 0; k < KS; ++k) {
            const int col = c * KS + k;
#pragma unroll
            for (int ko = 0; ko < KK; ++ko)
                acc[ko] += xv[k] * w[ko * CK + col];
        }
        __syncthreads();
    }
    float* ob = out + (size_t)b * KK * PP + p;
#pragma unroll
    for (int ko = 0; ko < KK; ++ko)
        ob[(size_t)ko * PP] = acc[ko];
}

extern "C" void kernel_launch(void* const* d_in, const int* in_sizes, int n_in,
                              void* d_out, int out_size, void* d_ws, size_t ws_size,
                              hipStream_t stream) {
    const float* x  = (const float*)d_in[0];
    const float* w  = (const float*)d_in[1];
    const int* idx  = (const int*)d_in[2];
    float* out      = (float*)d_out;

    const size_t xt_bytes = (size_t)BB * PP * CC * 2;    // 8,388,608
    const size_t need     = xt_bytes + (size_t)KK * CK * 2;

    if (ws_size >= need) {
        unsigned short* xt = (unsigned short*)d_ws;
        unsigned short* wa = (unsigned short*)((char*)d_ws + xt_bytes);
        const int wb_blocks = (KK * CK + 255) / 256;     // 72
        prep_kernel<<<512 + wb_blocks, 256, 0, stream>>>(x, w, xt, wa);
        abc_mfma9_kernel<<<BB * (PP / 128), 256, 0, stream>>>(xt, wa, idx, out);
    } else {
        abc_valu_kernel<<<BB * (PP / 256), 256, 0, stream>>>(x, w, idx, out);
    }
}